// Round 6
// baseline (71.906 us; speedup 1.0000x reference)
//
#include <hip/hip_runtime.h>

typedef float vf4 __attribute__((ext_vector_type(4)));

#define TWO_PI_F 6.283185307179586f
#define L2T_OVER_64 0.20762050594f  /* log2(10000)/64 */

// Single fused dispatch. Blocks come in pairs: even blockIdx -> feature
// gather-copy for a 16-row slab; odd blockIdx -> pos-embedding + mask for the
// same slab. N % 16 == 0 so every slab lives in ONE batch; each block
// recomputes its batch's exclusive offset (<=1 KB L1-hot scan of num_nodes)
// and, for emb blocks, the per-batch coordinate maxima (<=4 KB L2-hot
// centroid scan). Each wave owns 4 rows: feat waves keep 4 independent 1 KB
// loads in flight before storing (MLP), emb waves batch 4 rows of sincos.
__global__ __launch_bounds__(256) void fused_kernel(
    const float* __restrict__ patch,
    const float* __restrict__ centroid,
    const int* __restrict__ num_nodes,
    int N, int nshift,
    float* __restrict__ out_feat,
    float* __restrict__ out_mask,
    float* __restrict__ out_emb) {
    const int tid = threadIdx.x;
    const int lane = tid & 63;
    const int wave = tid >> 6;
    const int role = blockIdx.x & 1;
    const int slab = blockIdx.x >> 1;
    const int row_base = slab * 16;
    const int b = (nshift >= 0) ? (row_base >> nshift) : (row_base / N);
    const int jbase = row_base - b * N;

    __shared__ int s_i[4];
    __shared__ float s_x[4], s_y[4];

    // exclusive offset: sum num_nodes[0..b-1]
    int v = 0;
    for (int t0 = tid; t0 < b; t0 += 256) v += num_nodes[t0];
    for (int d = 1; d < 64; d <<= 1) v += __shfl_xor(v, d);
    if (lane == 0) s_i[wave] = v;
    __syncthreads();
    const int offset = s_i[0] + s_i[1] + s_i[2] + s_i[3];
    const int nn = num_nodes[b];
    const int n_eff = min(nn, N);

    if (role == 0) {
        // ---- features: 4 adjacent rows per wave, loads issued back-to-back ----
        const int j0 = jbase + wave * 4;
        const vf4* p0 = (const vf4*)(patch + (size_t)(offset + j0) * 256) + lane;
        vf4 f0 = (vf4)(0.0f), f1 = (vf4)(0.0f), f2 = (vf4)(0.0f), f3 = (vf4)(0.0f);
        if (j0 + 0 < n_eff) f0 = p0[0 * 64];
        if (j0 + 1 < n_eff) f1 = p0[1 * 64];
        if (j0 + 2 < n_eff) f2 = p0[2 * 64];
        if (j0 + 3 < n_eff) f3 = p0[3 * 64];
        vf4* o0 = (vf4*)(out_feat + (size_t)(row_base + wave * 4) * 256) + lane;
        o0[0 * 64] = f0;
        o0[1 * 64] = f1;
        o0[2 * 64] = f2;
        o0[3 * 64] = f3;
    } else {
        // ---- mask + sine embedding ----
        // per-batch maxima -> 2pi/(max+eps)
        float mx = 0.0f, my = 0.0f;   // zeros participate; coords >= 0
        for (int j = tid; j < n_eff; j += 256) {
            float2 c = ((const float2*)centroid)[offset + j];
            mx = fmaxf(mx, c.x);
            my = fmaxf(my, c.y);
        }
        for (int d = 1; d < 64; d <<= 1) {
            mx = fmaxf(mx, __shfl_xor(mx, d));
            my = fmaxf(my, __shfl_xor(my, d));
        }
        if (lane == 0) { s_x[wave] = mx; s_y[wave] = my; }
        __syncthreads();
        mx = fmaxf(fmaxf(s_x[0], s_x[1]), fmaxf(s_x[2], s_x[3]));
        my = fmaxf(fmaxf(s_y[0], s_y[1]), fmaxf(s_y[2], s_y[3]));
        const float ivx = TWO_PI_F / (mx + 1e-6f);
        const float ivy = TWO_PI_F / (my + 1e-6f);

        if (tid < 16)  // 16 mask values, one 64 B contiguous write
            out_mask[row_base + tid] = (jbase + tid >= nn + 1) ? 1.0f : 0.0f;

        const int m = lane & 31;  // emb elements 4m..4m+3 of this half
        const float inv0 = exp2f(-(float)(2 * m) * L2T_OVER_64);
        const float inv1 = exp2f(-(float)(2 * m + 1) * L2T_OVER_64);

        vf4* oe = (vf4*)(out_emb + (size_t)(row_base + wave * 4) * 256) + lane;
        #pragma unroll
        for (int r = 0; r < 4; ++r) {
            const int j = jbase + wave * 4 + r;
            float x = 0.0f, y = 0.0f;
            if (j < n_eff) {
                float2 c = ((const float2*)centroid)[offset + j];
                x = c.x; y = c.y;
            }
            const float a = (lane < 32) ? (y * ivy) : (x * ivx);
            float s0, c0, s1, c1;
            __sincosf(a * inv0, &s0, &c0);
            __sincosf(a * inv1, &s1, &c1);
            vf4 e = {s0, c0, s1, c1};
            oe[r * 64] = e;
        }
    }
}

extern "C" void kernel_launch(void* const* d_in, const int* in_sizes, int n_in,
                              void* d_out, int out_size, void* d_ws, size_t ws_size,
                              hipStream_t stream) {
    (void)n_in; (void)d_ws; (void)ws_size;
    const float* patch     = (const float*)d_in[0];
    const float* centroid  = (const float*)d_in[1];
    const int*   num_nodes = (const int*)d_in[2];

    const int B = in_sizes[2];                 // 256
    const int C = 256;                         // feature dim (fixed by problem)
    const int N = out_size / (B * (C + 257));  // 512

    int nshift = -1;
    if ((N & (N - 1)) == 0) {                  // pow2 -> shift instead of div
        int s = 0, v = N;
        while (v > 1) { v >>= 1; ++s; }
        nshift = s;
    }

    float* out_feat = (float*)d_out;
    float* out_mask = out_feat + (size_t)B * N * C;
    float* out_emb  = out_mask + (size_t)B * N;

    const int rows = B * N;                    // divisible by 16 (N % 16 == 0)
    const int slabs = rows / 16;
    fused_kernel<<<slabs * 2, 256, 0, stream>>>(
        patch, centroid, num_nodes, N, nshift, out_feat, out_mask, out_emb);
}

// Round 7
// 51.094 us; speedup vs baseline: 1.4073x; 1.4073x over previous
//
#include <hip/hip_runtime.h>

typedef float vf4 __attribute__((ext_vector_type(4)));

#define TWO_PI_F 6.283185307179586f
#define L2T_OVER_64 0.20762050594f  /* log2(10000)/64 */

// Single fused dispatch. Blocks come in pairs: even blockIdx -> feature
// gather-copy for an 8-row slab; odd blockIdx -> pos-embedding + mask for the
// same slab. N % 8 == 0 so every slab lives in ONE batch; each block
// recomputes its batch's exclusive offset (L1-hot scan of num_nodes) and, for
// emb blocks, the per-batch coordinate maxima (L2-hot centroid scan).
// Round-7 single change vs round 5: NONTEMPORAL STORES on all outputs so the
// 269 MB write stream doesn't thrash L2/L3 — inputs (79 MB) can then stay
// L3-resident across timed graph replays. Loads remain regular/cacheable.
__global__ __launch_bounds__(256) void fused_kernel(
    const float* __restrict__ patch,
    const float* __restrict__ centroid,
    const int* __restrict__ num_nodes,
    int N, int nshift,
    float* __restrict__ out_feat,
    float* __restrict__ out_mask,
    float* __restrict__ out_emb) {
    const int tid = threadIdx.x;
    const int lane = tid & 63;
    const int wave = tid >> 6;
    const int role = blockIdx.x & 1;
    const int slab = blockIdx.x >> 1;
    const int row_base = slab * 8;
    const int b = (nshift >= 0) ? (row_base >> nshift) : (row_base / N);
    const int jbase = row_base - b * N;

    __shared__ int s_i[4];
    __shared__ float s_x[4], s_y[4];

    // exclusive offset: sum num_nodes[0..b-1]
    int v = 0;
    for (int t0 = tid; t0 < b; t0 += 256) v += num_nodes[t0];
    for (int d = 1; d < 64; d <<= 1) v += __shfl_xor(v, d);
    if (lane == 0) s_i[wave] = v;
    __syncthreads();
    const int offset = s_i[0] + s_i[1] + s_i[2] + s_i[3];
    const int nn = num_nodes[b];
    const int n_eff = min(nn, N);

    if (role == 0) {
        // ---- features: 2 adjacent rows per wave (2 KB read, 2 KB write) ----
        const int j0 = jbase + wave * 2;
        vf4 f0 = (vf4)(0.0f), f1 = (vf4)(0.0f);
        if (j0 < n_eff)
            f0 = ((const vf4*)(patch + (size_t)(offset + j0) * 256))[lane];
        if (j0 + 1 < n_eff)
            f1 = ((const vf4*)(patch + (size_t)(offset + j0 + 1) * 256))[lane];
        const int row0 = row_base + wave * 2;
        vf4* o = (vf4*)(out_feat + (size_t)row0 * 256) + lane;
        __builtin_nontemporal_store(f0, o);
        __builtin_nontemporal_store(f1, o + 64);
    } else {
        // ---- mask + sine embedding ----
        // per-batch maxima -> 2pi/(max+eps)
        float mx = 0.0f, my = 0.0f;   // zeros participate; coords >= 0
        for (int j = tid; j < n_eff; j += 256) {
            float2 c = ((const float2*)centroid)[offset + j];
            mx = fmaxf(mx, c.x);
            my = fmaxf(my, c.y);
        }
        for (int d = 1; d < 64; d <<= 1) {
            mx = fmaxf(mx, __shfl_xor(mx, d));
            my = fmaxf(my, __shfl_xor(my, d));
        }
        if (lane == 0) { s_x[wave] = mx; s_y[wave] = my; }
        __syncthreads();
        mx = fmaxf(fmaxf(s_x[0], s_x[1]), fmaxf(s_x[2], s_x[3]));
        my = fmaxf(fmaxf(s_y[0], s_y[1]), fmaxf(s_y[2], s_y[3]));
        const float ivx = TWO_PI_F / (mx + 1e-6f);
        const float ivy = TWO_PI_F / (my + 1e-6f);

        if (tid < 8)   // 8 mask values, one 32 B contiguous write
            __builtin_nontemporal_store(
                (jbase + tid >= nn + 1) ? 1.0f : 0.0f, out_mask + row_base + tid);

        const int m = lane & 31;  // emb elements 4m..4m+3 of this half
        const float inv0 = exp2f(-(float)(2 * m) * L2T_OVER_64);
        const float inv1 = exp2f(-(float)(2 * m + 1) * L2T_OVER_64);

        #pragma unroll
        for (int r = 0; r < 2; ++r) {
            const int j = jbase + wave * 2 + r;
            float x = 0.0f, y = 0.0f;
            if (j < n_eff) {
                float2 c = ((const float2*)centroid)[offset + j];
                x = c.x; y = c.y;
            }
            const float a = (lane < 32) ? (y * ivy) : (x * ivx);
            float s0, c0, s1, c1;
            __sincosf(a * inv0, &s0, &c0);
            __sincosf(a * inv1, &s1, &c1);
            vf4 e = {s0, c0, s1, c1};
            vf4* oe = (vf4*)(out_emb + (size_t)(row_base + wave * 2 + r) * 256) + lane;
            __builtin_nontemporal_store(e, oe);
        }
    }
}

extern "C" void kernel_launch(void* const* d_in, const int* in_sizes, int n_in,
                              void* d_out, int out_size, void* d_ws, size_t ws_size,
                              hipStream_t stream) {
    (void)n_in; (void)d_ws; (void)ws_size;
    const float* patch     = (const float*)d_in[0];
    const float* centroid  = (const float*)d_in[1];
    const int*   num_nodes = (const int*)d_in[2];

    const int B = in_sizes[2];                 // 256
    const int C = 256;                         // feature dim (fixed by problem)
    const int N = out_size / (B * (C + 257));  // 512

    int nshift = -1;
    if ((N & (N - 1)) == 0) {                  // pow2 -> shift instead of div
        int s = 0, v = N;
        while (v > 1) { v >>= 1; ++s; }
        nshift = s;
    }

    float* out_feat = (float*)d_out;
    float* out_mask = out_feat + (size_t)B * N * C;
    float* out_emb  = out_mask + (size_t)B * N;

    const int rows = B * N;                    // divisible by 8 (N % 8 == 0)
    const int slabs = rows / 8;
    fused_kernel<<<slabs * 2, 256, 0, stream>>>(
        patch, centroid, num_nodes, N, nshift, out_feat, out_mask, out_emb);
}